// Round 1
// baseline (613.969 us; speedup 1.0000x reference)
//
#include <hip/hip_runtime.h>
#include <stdint.h>
#include <math.h>

// ---------------------------------------------------------------------------
// GraphDistillOperatorWithEdgeWeight, N=8192, F=256, OUT=256
//
// Math (after simplification):
//   E_ij = exp(5*adj_ij), E_ii = 0            (no max-subtract needed: arg<=5)
//   s_i  = sum_j E_ij ;  a = E / s
//   agg  = a @ features ; kagg = a @ key_features
//   R    = features - ([features|agg] @ W_d + b_d)
//   out1 = tanh(R @ W_o + b_o)
//   Kin  = key + (kagg @ W_a + b_a)
//   out2 = tanh(Kin @ W_ao + b_ao)
//
// Kernel plan:
//   transpose_f32_bf16 x6 : Xt = [feat|key]^T (bf16, B^T layout), W*^T (bf16)
//   pack_feat             : XcatN[:,0:256] = bf16(features)
//   exp_gemm              : fused exp + (E @ X) with K-split 2, partials f32
//                           - B read per-lane direct from global (no LDS)
//                           - A (adj tile) via 4-slot LDS ring + 4-deep reg queue
//                           - manual "s_waitcnt lgkmcnt(0); s_barrier" so the
//                             global-load pipeline survives the barrier
//   finalize_agg          : U/s -> XcatN[:,256:512] (agg), Kagg (bf16)
//   gemm_small<EPI> x4    : the trailing chain (16x16x32 bf16 MFMA)
// ---------------------------------------------------------------------------

typedef __attribute__((ext_vector_type(8)))  short bf16x8_t;  // 8 bf16 = 4 VGPR
typedef __attribute__((ext_vector_type(4)))  float f32x4_t;   // 16x16 acc
typedef __attribute__((ext_vector_type(16))) float f32x16_t;  // 32x32 acc

#define MFMA32(A, B, C) __builtin_amdgcn_mfma_f32_32x32x16_bf16(A, B, C, 0, 0, 0)
#define MFMA16(A, B, C) __builtin_amdgcn_mfma_f32_16x16x32_bf16(A, B, C, 0, 0, 0)

__device__ __forceinline__ unsigned short f2bf(float x) {
    union { float f; unsigned u; } c; c.f = x;
    unsigned u = c.u;
    return (unsigned short)((u + 0x7fffu + ((u >> 16) & 1u)) >> 16);  // RNE
}

// ---------------------------------------------------------------------------
// Generic 32x32 LDS-tiled transpose: dst[c][r] = bf16(src[r][c]).
// R, C multiples of 32. grid = (R/32, C/32), block = 256.
// ---------------------------------------------------------------------------
__global__ __launch_bounds__(256) void transpose_f32_bf16(
    const float* __restrict__ src, unsigned short* __restrict__ dst, int R, int C)
{
    __shared__ float tile[32][33];
    const int x  = threadIdx.x & 31;
    const int y4 = (threadIdx.x >> 5) * 4;
    const int r0 = blockIdx.x * 32;
    const int c0 = blockIdx.y * 32;
#pragma unroll
    for (int i = 0; i < 4; ++i)
        tile[y4 + i][x] = src[(size_t)(r0 + y4 + i) * C + c0 + x];
    __syncthreads();
#pragma unroll
    for (int i = 0; i < 4; ++i)
        dst[(size_t)(c0 + y4 + i) * R + r0 + x] = f2bf(tile[x][y4 + i]);
}

// XcatN[:, 0:256] = bf16(features). grid = 8192, block = 256.
__global__ __launch_bounds__(256) void pack_feat(
    const float* __restrict__ src, unsigned short* __restrict__ dst)
{
    const size_t idx = (size_t)blockIdx.x * 256 + threadIdx.x;
    const size_t row = idx >> 8;
    const int col = (int)(idx & 255);
    dst[row * 512 + col] = f2bf(src[idx]);
}

// ---------------------------------------------------------------------------
// exp_gemm: U_part = E_slice @ X, rowsum partials.
// grid = 256 blocks (128 row-blocks x 2 K-halves), block = 512 (8 waves).
// Per block: rows 64, cols 512, K-slice 4096 (128 iters of K=32).
// ---------------------------------------------------------------------------
#define NITER 128

__device__ __forceinline__ void stage_tile(float4 v, int j2, int kbase, int skoff,
                                           int sgrow, unsigned short* sp, float& rs)
{
    float e0 = __expf(5.f * v.x);
    float e1 = __expf(5.f * v.y);
    float e2 = __expf(5.f * v.z);
    float e3 = __expf(5.f * v.w);
    const int gk = kbase + j2 * 32 + skoff;
    if (gk + 0 == sgrow) e0 = 0.f;   // diagonal (self-loop) mask
    if (gk + 1 == sgrow) e1 = 0.f;
    if (gk + 2 == sgrow) e2 = 0.f;
    if (gk + 3 == sgrow) e3 = 0.f;
    rs += (e0 + e1) + (e2 + e3);     // rowsum from full-f32 values
    uint2 p;
    p.x = (unsigned)f2bf(e0) | ((unsigned)f2bf(e1) << 16);
    p.y = (unsigned)f2bf(e2) | ((unsigned)f2bf(e3) << 16);
    *(uint2*)sp = p;
}

__global__ __launch_bounds__(512) void exp_gemm(
    const float* __restrict__ adj, const unsigned short* __restrict__ Xt,
    float* __restrict__ Upart, float* __restrict__ sSpart)
{
    __shared__ unsigned short sA[4][64 * 32];   // 4-slot ring, 2 KB/slot

    const int t    = threadIdx.x;
    const int w    = t >> 6;        // wave 0..7
    const int lane = t & 63;
    const int q    = lane >> 5;     // half-wave
    const int l31  = lane & 31;
    const int rblk = blockIdx.x >> 1;
    const int h    = blockIdx.x & 1;
    const int row0 = rblk * 64;
    const int kbase = h * 4096;

    // stager role: thread owns (row srow, k-slice skoff..skoff+3) each iter
    const int srow  = t >> 3;          // 0..63
    const int skoff = (t & 7) * 4;     // 8 threads x float4 = 128 B per row
    const int sgrow = row0 + srow;
    const float* adj_row = adj + (size_t)sgrow * 8192 + kbase + skoff;
    unsigned short* sWp = &sA[0][0] + srow * 32 + skoff;

    // B: wave w owns n-tiles at w*64 and w*64+32; per-lane direct global reads.
    const unsigned short* bptr0 = Xt + (size_t)(w * 64 + l31) * 8192 + kbase + q * 8;
    const unsigned short* bptr1 = bptr0 + (size_t)32 * 8192;

    float rs = 0.f;
    f32x16_t acc[2][2];
#pragma unroll
    for (int a = 0; a < 2; ++a)
#pragma unroll
        for (int b = 0; b < 2; ++b)
#pragma unroll
            for (int e = 0; e < 16; ++e) acc[a][b][e] = 0.f;

    float4   qa[4];         // adj prefetch queue (data for iters i..i+3)
    bf16x8_t bq[2][2][2];   // [parity][ntile][kstep16] B fragments

#define LOADB(J, PAR) do {                                                  \
        int jc_ = (J); if (jc_ >= NITER) jc_ = 0;                           \
        bq[PAR][0][0] = *(const bf16x8_t*)(bptr0 + (size_t)jc_ * 32);       \
        bq[PAR][0][1] = *(const bf16x8_t*)(bptr0 + (size_t)jc_ * 32 + 16);  \
        bq[PAR][1][0] = *(const bf16x8_t*)(bptr1 + (size_t)jc_ * 32);       \
        bq[PAR][1][1] = *(const bf16x8_t*)(bptr1 + (size_t)jc_ * 32 + 16);  \
    } while (0)

    // prologue: fill queue (iters 0..3), stage iters 0,1, prefetch B for 0
    qa[0] = *(const float4*)(adj_row + 0);
    qa[1] = *(const float4*)(adj_row + 32);
    qa[2] = *(const float4*)(adj_row + 64);
    qa[3] = *(const float4*)(adj_row + 96);
    stage_tile(qa[0], 0, kbase, skoff, sgrow, sWp + 0 * 2048, rs);
    stage_tile(qa[1], 1, kbase, skoff, sgrow, sWp + 1 * 2048, rs);
    LOADB(0, 0);
    asm volatile("s_waitcnt lgkmcnt(0)\n\ts_barrier" ::: "memory");

    for (int ib = 0; ib < NITER; ib += 4) {
#pragma unroll
        for (int u = 0; u < 4; ++u) {
            const int i = ib + u;
            // adj prefetch for iter i+4 (slot (i+4)%4 == u); clamp tail
            {
                int j = i + 4; if (j >= NITER) j = 0;
                qa[u] = *(const float4*)(adj_row + (size_t)j * 32);
            }
            // B prefetch for iter i+1
            LOADB(i + 1, (u + 1) & 1);
            // stage A for iter i+2 into ring slot (i+2)%4 (data loaded 2 iters ago)
            if (i + 2 < NITER)
                stage_tile(qa[(u + 2) & 3], i + 2, kbase, skoff, sgrow,
                           sWp + ((u + 2) & 3) * 2048, rs);
            // barrier WITHOUT vmcnt drain: LDS writes flushed, HBM pipeline kept
            asm volatile("s_waitcnt lgkmcnt(0)\n\ts_barrier" ::: "memory");
            // compute iter i from slot i%4 == u
            const unsigned short* sa = &sA[u][0];
            const int ao = l31 * 32 + q * 8;
            bf16x8_t a00 = *(const bf16x8_t*)(sa + ao);
            bf16x8_t a01 = *(const bf16x8_t*)(sa + ao + 16);
            bf16x8_t a10 = *(const bf16x8_t*)(sa + ao + 1024);
            bf16x8_t a11 = *(const bf16x8_t*)(sa + ao + 1024 + 16);
            const int p = u & 1;
            acc[0][0] = MFMA32(a00, bq[p][0][0], acc[0][0]);
            acc[1][0] = MFMA32(a10, bq[p][0][0], acc[1][0]);
            acc[0][1] = MFMA32(a00, bq[p][1][0], acc[0][1]);
            acc[1][1] = MFMA32(a10, bq[p][1][0], acc[1][1]);
            acc[0][0] = MFMA32(a01, bq[p][0][1], acc[0][0]);
            acc[1][0] = MFMA32(a11, bq[p][0][1], acc[1][0]);
            acc[0][1] = MFMA32(a01, bq[p][1][1], acc[0][1]);
            acc[1][1] = MFMA32(a11, bq[p][1][1], acc[1][1]);
        }
    }
#undef LOADB

    // rowsum partial: 8 stager threads per row, butterfly within groups of 8
    rs += __shfl_xor(rs, 1);
    rs += __shfl_xor(rs, 2);
    rs += __shfl_xor(rs, 4);
    if ((t & 7) == 0) sSpart[h * 8192 + row0 + (t >> 3)] = rs;

    // write f32 partial tile  (C layout: col=lane&31, row=(reg&3)+8*(reg>>2)+4*q)
    float* up = Upart + (size_t)h * 8192 * 512 + (size_t)row0 * 512;
#pragma unroll
    for (int mt = 0; mt < 2; ++mt)
#pragma unroll
        for (int nt = 0; nt < 2; ++nt) {
            const int col = w * 64 + nt * 32 + l31;
#pragma unroll
            for (int reg = 0; reg < 16; ++reg) {
                const int lrow = (reg & 3) + 8 * (reg >> 2) + 4 * q + mt * 32;
                up[(size_t)lrow * 512 + col] = acc[mt][nt][reg];
            }
        }
}

// ---------------------------------------------------------------------------
// finalize: U = Upart0+Upart1, s = s0+s1; agg -> XcatN[:,256:512], kagg -> Kagg
// grid = 8192 (one row per block), block = 256.
// ---------------------------------------------------------------------------
__global__ __launch_bounds__(256) void finalize_agg(
    const float* __restrict__ Upart, const float* __restrict__ sSpart,
    unsigned short* __restrict__ XcatN, unsigned short* __restrict__ Kagg)
{
    const int row = blockIdx.x;
    const int t = threadIdx.x;
    const float* u0 = Upart + (size_t)row * 512;
    const float* u1 = u0 + (size_t)8192 * 512;
    const float inv = 1.f / (sSpart[row] + sSpart[8192 + row]);
    const float aggv  = (u0[t]       + u1[t])       * inv;
    const float kaggv = (u0[t + 256] + u1[t + 256]) * inv;
    XcatN[(size_t)row * 512 + 256 + t] = f2bf(aggv);
    Kagg [(size_t)row * 256 + t]       = f2bf(kaggv);
}

// ---------------------------------------------------------------------------
// gemm_small: C[M,N=256] = A[M,K]_bf16 @ Wt[N,K]_bf16 + bias, fused epilogue.
// EPI 0: out_bf16 = aux - C ; EPI 1: out_bf16 = aux + C ; EPI 2: out_f32 = tanh(C)
// grid = 256 (BM=32), block = 256 (4 waves), 16x16x32 MFMA.
// ---------------------------------------------------------------------------
template <int EPI>
__global__ __launch_bounds__(256) void gemm_small(
    const unsigned short* __restrict__ A, const unsigned short* __restrict__ Wt,
    const float* __restrict__ bias, const float* __restrict__ aux,
    void* __restrict__ outp, int K)
{
    __shared__ unsigned short sA[32 * 32];
    __shared__ unsigned short sB[256 * 32];
    __shared__ float sBias[256];

    const int t = threadIdx.x;
    const int w = t >> 6, lane = t & 63;
    const int m_lo = lane & 15, quad = lane >> 4;
    const int row0 = blockIdx.x * 32;
    sBias[t] = bias[t];

    f32x4_t acc[2][4];
#pragma unroll
    for (int a = 0; a < 2; ++a)
#pragma unroll
        for (int b = 0; b < 4; ++b)
#pragma unroll
            for (int e = 0; e < 4; ++e) acc[a][b][e] = 0.f;

    const int nsteps = K >> 5;
    for (int ks = 0; ks < nsteps; ++ks) {
        const int k0 = ks * 32;
        __syncthreads();  // previous iteration's reads done before re-staging
        if (t < 128) {    // A tile: 32 rows x 32 k
            bf16x8_t v = *(const bf16x8_t*)(A + (size_t)(row0 + (t >> 2)) * K + k0 + (t & 3) * 8);
            *(bf16x8_t*)(&sA[(t >> 2) * 32 + (t & 3) * 8]) = v;
        }
        {                 // B tile: 256 n-rows x 32 k, thread t stages row t
            const unsigned short* src = Wt + (size_t)t * K + k0;
            unsigned short* dst = &sB[t * 32];
            *(bf16x8_t*)(dst +  0) = *(const bf16x8_t*)(src +  0);
            *(bf16x8_t*)(dst +  8) = *(const bf16x8_t*)(src +  8);
            *(bf16x8_t*)(dst + 16) = *(const bf16x8_t*)(src + 16);
            *(bf16x8_t*)(dst + 24) = *(const bf16x8_t*)(src + 24);
        }
        __syncthreads();
        bf16x8_t a0 = *(const bf16x8_t*)(&sA[m_lo * 32 + quad * 8]);
        bf16x8_t a1 = *(const bf16x8_t*)(&sA[(16 + m_lo) * 32 + quad * 8]);
#pragma unroll
        for (int nt = 0; nt < 4; ++nt) {
            bf16x8_t b = *(const bf16x8_t*)(&sB[(w * 64 + nt * 16 + m_lo) * 32 + quad * 8]);
            acc[0][nt] = MFMA16(a0, b, acc[0][nt]);
            acc[1][nt] = MFMA16(a1, b, acc[1][nt]);
        }
    }

    // epilogue (C layout: col=lane&15, row=quad*4+reg)
#pragma unroll
    for (int mt = 0; mt < 2; ++mt)
#pragma unroll
        for (int nt = 0; nt < 4; ++nt) {
            const int col = w * 64 + nt * 16 + m_lo;
#pragma unroll
            for (int r = 0; r < 4; ++r) {
                const int row = row0 + mt * 16 + quad * 4 + r;
                const float c = acc[mt][nt][r] + sBias[col];
                if (EPI == 0)
                    ((unsigned short*)outp)[(size_t)row * 256 + col] =
                        f2bf(aux[(size_t)row * 256 + col] - c);
                else if (EPI == 1)
                    ((unsigned short*)outp)[(size_t)row * 256 + col] =
                        f2bf(aux[(size_t)row * 256 + col] + c);
                else
                    ((float*)outp)[(size_t)row * 256 + col] = tanhf(c);
            }
        }
}

// ---------------------------------------------------------------------------
extern "C" void kernel_launch(void* const* d_in, const int* in_sizes, int n_in,
                              void* d_out, int out_size, void* d_ws, size_t ws_size,
                              hipStream_t stream) {
    const float* features = (const float*)d_in[0];
    const float* key      = (const float*)d_in[1];
    const float* adj      = (const float*)d_in[2];
    const float* W_d  = (const float*)d_in[3];
    const float* b_d  = (const float*)d_in[4];
    const float* W_o  = (const float*)d_in[5];
    const float* b_o  = (const float*)d_in[6];
    const float* W_a  = (const float*)d_in[7];
    const float* b_a  = (const float*)d_in[8];
    const float* W_ao = (const float*)d_in[9];
    const float* b_ao = (const float*)d_in[10];

    float* out1 = (float*)d_out;
    float* out2 = out1 + (size_t)8192 * 256;

    char* ws = (char*)d_ws;
    unsigned short* Xt    = (unsigned short*)(ws);               // [512][8192] bf16, 8 MB
    unsigned short* XcatN = (unsigned short*)(ws +  8388608);    // [8192][512] bf16, 8 MB
    unsigned short* Kagg  = (unsigned short*)(ws + 16777216);    // [8192][256] bf16, 4 MB
    float*          Upart = (float*)        (ws + 20971520);     // [2][8192][512] f32, 32 MB
    float*          sSp   = (float*)        (ws + 54525952);     // [2][8192] f32
    unsigned short* Wd_t  = (unsigned short*)(ws + 54591488);    // [256][512]
    unsigned short* Wo_t  = (unsigned short*)(ws + 54853632);    // [256][256]
    unsigned short* Wa_t  = (unsigned short*)(ws + 54984704);
    unsigned short* Wao_t = (unsigned short*)(ws + 55115776);
    unsigned short* R     = Xt;                                  // alias (Xt dead after exp_gemm)
    unsigned short* Kin   = (unsigned short*)(ws + 4194304);     // alias, upper half of Xt

    dim3 blk(256);
    // prep: transposes + packs (bf16)
    transpose_f32_bf16<<<dim3(256, 8), blk, 0, stream>>>(features, Xt, 8192, 256);
    transpose_f32_bf16<<<dim3(256, 8), blk, 0, stream>>>(key, Xt + (size_t)256 * 8192, 8192, 256);
    transpose_f32_bf16<<<dim3(16, 8),  blk, 0, stream>>>(W_d,  Wd_t,  512, 256);
    transpose_f32_bf16<<<dim3(8, 8),   blk, 0, stream>>>(W_o,  Wo_t,  256, 256);
    transpose_f32_bf16<<<dim3(8, 8),   blk, 0, stream>>>(W_a,  Wa_t,  256, 256);
    transpose_f32_bf16<<<dim3(8, 8),   blk, 0, stream>>>(W_ao, Wao_t, 256, 256);
    pack_feat<<<8192, blk, 0, stream>>>(features, XcatN);

    // fused exp-softmax GEMM (partials) + normalize
    exp_gemm<<<256, dim3(512), 0, stream>>>(adj, Xt, Upart, sSp);
    finalize_agg<<<8192, blk, 0, stream>>>(Upart, sSp, XcatN, Kagg);

    // trailing chain
    gemm_small<0><<<256, blk, 0, stream>>>(XcatN, Wd_t, b_d, features, (void*)R,   512);
    gemm_small<1><<<256, blk, 0, stream>>>(Kagg,  Wa_t, b_a, key,      (void*)Kin, 256);
    gemm_small<2><<<256, blk, 0, stream>>>(R,     Wo_t, b_o, nullptr,  (void*)out1, 256);
    gemm_small<2><<<256, blk, 0, stream>>>(Kin,   Wao_t, b_ao, nullptr, (void*)out2, 256);
}

// Round 2
// 590.320 us; speedup vs baseline: 1.0401x; 1.0401x over previous
//
#include <hip/hip_runtime.h>
#include <stdint.h>
#include <math.h>

// ---------------------------------------------------------------------------
// GraphDistillOperatorWithEdgeWeight, N=8192, F=256, OUT=256
//
//   E_ij = exp(5*adj_ij), E_ii = 0 ; s_i = sum_j E_ij ; a = E/s
//   agg = a@feat ; kagg = a@key
//   out1 = tanh(Xcat @ W1 + c1),  Xcat=[feat|agg],  W1=[[W_o],[0]] - W_d@W_o,
//                                 c1 = b_o - b_d@W_o
//   out2 = tanh(Kcat @ W2 + c2),  Kcat=[key|kagg],  W2=[[W_ao],[W_a@W_ao]],
//                                 c2 = b_ao + b_a@W_ao
// ---------------------------------------------------------------------------

typedef __attribute__((ext_vector_type(4)))  short bf16x4_t;
typedef __attribute__((ext_vector_type(8)))  short bf16x8_t;
typedef __attribute__((ext_vector_type(4)))  float f32x4_t;
typedef __attribute__((ext_vector_type(16))) float f32x16_t;

#define MFMA32(A, B, C) __builtin_amdgcn_mfma_f32_32x32x16_bf16(A, B, C, 0, 0, 0)
#define MFMA16(A, B, C) __builtin_amdgcn_mfma_f32_16x16x32_bf16(A, B, C, 0, 0, 0)

__device__ __forceinline__ unsigned short f2bf(float x) {
    union { float f; unsigned u; } c; c.f = x;
    unsigned u = c.u;
    return (unsigned short)((u + 0x7fffu + ((u >> 16) & 1u)) >> 16);  // RNE
}
__device__ __forceinline__ unsigned pack2bf(float a, float b) {
    return (unsigned)f2bf(a) | ((unsigned)f2bf(b) << 16);
}
__device__ __forceinline__ float bflo(unsigned u) {
    union { unsigned u; float f; } c; c.u = u << 16; return c.f;
}
__device__ __forceinline__ float bfhi(unsigned u) {
    union { unsigned u; float f; } c; c.u = u & 0xffff0000u; return c.f;
}

// ---------------------------------------------------------------------------
// 32x32 tiled transpose: dst[c][r] = bf16(src[r][c]). grid=(R/32, C/32).
// ---------------------------------------------------------------------------
__global__ __launch_bounds__(256) void transpose_f32_bf16(
    const float* __restrict__ src, unsigned short* __restrict__ dst, int R, int C)
{
    __shared__ float tile[32][33];
    const int x  = threadIdx.x & 31;
    const int y4 = (threadIdx.x >> 5) * 4;
    const int r0 = blockIdx.x * 32;
    const int c0 = blockIdx.y * 32;
#pragma unroll
    for (int i = 0; i < 4; ++i)
        tile[y4 + i][x] = src[(size_t)(r0 + y4 + i) * C + c0 + x];
    __syncthreads();
#pragma unroll
    for (int i = 0; i < 4; ++i)
        dst[(size_t)(c0 + y4 + i) * R + r0 + x] = f2bf(tile[x][y4 + i]);
}

// dst row-major uint rows of 256 (=512 bf16 cols), fill cols 0..255.
// grid = 4096, block = 256.
__global__ __launch_bounds__(256) void pack_half(
    const float* __restrict__ src, unsigned* __restrict__ dst)
{
    const int idx = blockIdx.x * 256 + threadIdx.x;
    const int row = idx >> 7, cp = idx & 127;
    float2 v = *(const float2*)(src + (size_t)row * 256 + cp * 2);
    dst[(size_t)row * 256 + cp] = pack2bf(v.x, v.y);
}

// ---------------------------------------------------------------------------
// Weight composition. compose1: W1t[n][k] = (k<256? W_o[k][n]:0) - (W_d@W_o)[k][n]
// compose2: W2t[n][k] = k<256 ? W_ao[k][n] : (W_a@W_ao)[k-256][n]. grid=512.
// ---------------------------------------------------------------------------
__global__ __launch_bounds__(256) void compose1(
    const float* __restrict__ W_d, const float* __restrict__ W_o,
    unsigned short* __restrict__ W1t)
{
    __shared__ float wrow[256];
    const int k = blockIdx.x, t = threadIdx.x;
    wrow[t] = W_d[(size_t)k * 256 + t];
    __syncthreads();
    float acc = 0.f;
#pragma unroll 8
    for (int m = 0; m < 256; ++m) acc = fmaf(wrow[m], W_o[(size_t)m * 256 + t], acc);
    const float v = (k < 256 ? W_o[(size_t)k * 256 + t] : 0.f) - acc;
    W1t[(size_t)t * 512 + k] = f2bf(v);
}

__global__ __launch_bounds__(256) void compose2(
    const float* __restrict__ W_a, const float* __restrict__ W_ao,
    unsigned short* __restrict__ W2t)
{
    __shared__ float wrow[256];
    const int k = blockIdx.x, t = threadIdx.x;
    float v;
    if (k < 256) {
        v = W_ao[(size_t)k * 256 + t];
    } else {
        wrow[t] = W_a[(size_t)(k - 256) * 256 + t];
        __syncthreads();
        float acc = 0.f;
#pragma unroll 8
        for (int m = 0; m < 256; ++m) acc = fmaf(wrow[m], W_ao[(size_t)m * 256 + t], acc);
        v = acc;
    }
    W2t[(size_t)t * 512 + k] = f2bf(v);
}

__global__ __launch_bounds__(256) void biasC(
    const float* __restrict__ b_d, const float* __restrict__ b_o,
    const float* __restrict__ b_a, const float* __restrict__ b_ao,
    const float* __restrict__ W_o, const float* __restrict__ W_ao,
    float* __restrict__ c1, float* __restrict__ c2)
{
    const int t = threadIdx.x;
    float a1 = 0.f, a2 = 0.f;
#pragma unroll 8
    for (int m = 0; m < 256; ++m) {
        a1 = fmaf(b_d[m], W_o [(size_t)m * 256 + t], a1);
        a2 = fmaf(b_a[m], W_ao[(size_t)m * 256 + t], a2);
    }
    c1[t] = b_o[t] - a1;
    c2[t] = b_ao[t] + a2;
}

// ---------------------------------------------------------------------------
// exp_gemm: Upart[h] = bf16( E_slice @ [feat|key] ), rowsum partials f32.
// grid = 256 (64 rowblocks x 4 K-split), block = 1024 (16 waves).
// Block tile: 128 rows x 512 cols, K-slice 2048. Wave tile: 128 x 32.
// Chunked K-loop: 4 ksteps per phase, double-buffered LDS, ONE lgkm-only
// barrier per phase (global-load pipeline is never drained).
// ---------------------------------------------------------------------------
#define ROWS 128
#define KSLICE 2048
#define NIT 64      // k-steps of 32
#define NCH 16      // chunks of 4 k-steps
#define ASTRIDE 36  // padded LDS row stride (shorts): 72 B -> 2-way max

__global__ __launch_bounds__(1024) void exp_gemm(
    const float* __restrict__ adj, const unsigned short* __restrict__ Xt,
    unsigned short* __restrict__ Upart, float* __restrict__ sSp)
{
    __shared__ unsigned short sA[2][4][ROWS * ASTRIDE];  // 72 KB

    const int t = threadIdx.x;
    const int w = t >> 6, lane = t & 63, q = lane >> 5, l31 = lane & 31;
    const int rb = blockIdx.x >> 2, h = blockIdx.x & 3;
    const int row0 = rb * ROWS, kbase = h * KSLICE;

    // stager role: row srow, k-offset skoff (8 threads x float4 per 32-k row)
    const int srow = t >> 3, skoff = (t & 7) * 4;
    const int sgrow = row0 + srow;
    const float* adj_row = adj + (size_t)sgrow * 8192 + kbase + skoff;
    const int swoff = srow * ASTRIDE + skoff;

    // B: wave w owns cols w*32..w*32+31, per-lane direct global reads
    const unsigned short* bptr = Xt + (size_t)(w * 32 + l31) * 8192 + kbase + q * 8;

    float rs = 0.f;
    f32x16_t acc[4];
#pragma unroll
    for (int mt = 0; mt < 4; ++mt)
#pragma unroll
        for (int e = 0; e < 16; ++e) acc[mt][e] = 0.f;

    bf16x8_t bq[4][2];      // B ring: slot = iter&3, [ksub]
    float4 qaA[4], qaB[4];  // adj double-buffer (one chunk each)

    auto stageChunk = [&](int cidx, const float4 (&qa)[4], int buf) {
        unsigned short* sb = &sA[buf][0][0] + swoff;
#pragma unroll
        for (int ks = 0; ks < 4; ++ks) {
            const float4 v = qa[ks];
            float e0 = __expf(5.f * v.x);
            float e1 = __expf(5.f * v.y);
            float e2 = __expf(5.f * v.z);
            float e3 = __expf(5.f * v.w);
            const int gk = kbase + (cidx * 4 + ks) * 32 + skoff;
            if (gk + 0 == sgrow) e0 = 0.f;   // diagonal mask
            if (gk + 1 == sgrow) e1 = 0.f;
            if (gk + 2 == sgrow) e2 = 0.f;
            if (gk + 3 == sgrow) e3 = 0.f;
            rs += (e0 + e1) + (e2 + e3);
            uint2 p; p.x = pack2bf(e0, e1); p.y = pack2bf(e2, e3);
            *(uint2*)(sb + ks * (ROWS * ASTRIDE)) = p;
        }
    };

    auto phase = [&](int c, float4 (&qaPre)[4], const float4 (&qaStg)[4], int buf) {
        // adj prefetch for chunk c+2 (used next phase)
        if (c + 2 < NCH) {
#pragma unroll
            for (int ks = 0; ks < 4; ++ks)
                qaPre[ks] = *(const float4*)(adj_row + (size_t)((c + 2) * 4 + ks) * 32);
        }
        // stage chunk c+1 into the other buffer (overlaps this phase's MFMA)
        if (c + 1 < NCH) stageChunk(c + 1, qaStg, buf ^ 1);
        // compute chunk c
#pragma unroll
        for (int u = 0; u < 4; ++u) {
            const int j = c * 4 + u;
            int jn = j + 2; if (jn >= NIT) jn = 0;   // B prefetch 2 iters ahead
            bq[(u + 2) & 3][0] = *(const bf16x8_t*)(bptr + (size_t)jn * 32);
            bq[(u + 2) & 3][1] = *(const bf16x8_t*)(bptr + (size_t)jn * 32 + 16);
            const unsigned short* sa = &sA[buf][u][0] + l31 * ASTRIDE + q * 8;
#pragma unroll
            for (int s = 0; s < 2; ++s)
#pragma unroll
                for (int mt = 0; mt < 4; ++mt) {
                    const unsigned short* p = sa + mt * (32 * ASTRIDE) + s * 16;
                    bf16x4_t lo = *(const bf16x4_t*)p;
                    bf16x4_t hi = *(const bf16x4_t*)(p + 4);
                    bf16x8_t a = __builtin_shufflevector(lo, hi, 0, 1, 2, 3, 4, 5, 6, 7);
                    acc[mt] = MFMA32(a, bq[u][s], acc[mt]);
                }
        }
        // lgkm-only barrier: LDS flushed, HBM/L2 load queue stays in flight
        asm volatile("s_waitcnt lgkmcnt(0)\n\ts_barrier" ::: "memory");
    };

    // prologue: adj chunks 0,1; stage chunk 0; B iters 0,1
#pragma unroll
    for (int ks = 0; ks < 4; ++ks)
        qaA[ks] = *(const float4*)(adj_row + (size_t)ks * 32);
#pragma unroll
    for (int ks = 0; ks < 4; ++ks)
        qaB[ks] = *(const float4*)(adj_row + (size_t)(4 + ks) * 32);
    stageChunk(0, qaA, 0);
    bq[0][0] = *(const bf16x8_t*)(bptr + 0);
    bq[0][1] = *(const bf16x8_t*)(bptr + 16);
    bq[1][0] = *(const bf16x8_t*)(bptr + 32);
    bq[1][1] = *(const bf16x8_t*)(bptr + 48);
    asm volatile("s_waitcnt lgkmcnt(0)\n\ts_barrier" ::: "memory");

    for (int c0 = 0; c0 < NCH; c0 += 2) {
        phase(c0,     qaA, qaB, 0);
        phase(c0 + 1, qaB, qaA, 1);
    }

    // rowsum partial: 8 stager threads per row
    rs += __shfl_xor(rs, 1);
    rs += __shfl_xor(rs, 2);
    rs += __shfl_xor(rs, 4);
    if ((t & 7) == 0) sSp[h * 8192 + sgrow] = rs;

    // store bf16 partial tile (C layout: col=lane&31, row=(reg&3)+8*(reg>>2)+4*q)
    unsigned short* up = Upart + (size_t)h * (8192 * 512) + (size_t)row0 * 512 + (w * 32 + l31);
#pragma unroll
    for (int mt = 0; mt < 4; ++mt)
#pragma unroll
        for (int reg = 0; reg < 16; ++reg) {
            const int lrow = mt * 32 + (reg & 3) + 8 * (reg >> 2) + 4 * q;
            up[(size_t)lrow * 512] = f2bf(acc[mt][reg]);
        }
}

// ---------------------------------------------------------------------------
// finalize: sum 4 bf16 partials, normalize; agg -> XcatN[:,256:512],
// kagg -> Kcat[:,256:512]. grid = 8192, block = 256 (2 cols/thread).
// ---------------------------------------------------------------------------
__global__ __launch_bounds__(256) void finalize_agg(
    const unsigned* __restrict__ Upart, const float* __restrict__ sSp,
    unsigned* __restrict__ XcatN, unsigned* __restrict__ Kcat)
{
    const int row = blockIdx.x, t = threadIdx.x;
    const float inv = 1.f / (sSp[row] + sSp[8192 + row] + sSp[16384 + row] + sSp[24576 + row]);
    const unsigned* u = Upart + (size_t)row * 256 + t;
    float lo = 0.f, hi = 0.f;
#pragma unroll
    for (int hh = 0; hh < 4; ++hh) {
        const unsigned v = u[(size_t)hh * (8192 * 256)];
        lo += bflo(v); hi += bfhi(v);
    }
    const unsigned res = pack2bf(lo * inv, hi * inv);
    if (t < 128) XcatN[(size_t)row * 256 + 128 + t] = res;
    else         Kcat [(size_t)row * 256 + t];          // placate: see below
    if (t >= 128) Kcat[(size_t)row * 256 + t] = res;    // cols 256.. -> uint 128..255
}

// ---------------------------------------------------------------------------
// gemm_out: out[8192][256] f32 = tanh(A[8192][512]bf16 @ Wt[256][512]^T + c).
// grid = 256 (Mtile 32), block = 256 (4 waves). Padded LDS (stride 36).
// ---------------------------------------------------------------------------
__global__ __launch_bounds__(256) void gemm_out(
    const unsigned short* __restrict__ A, const unsigned short* __restrict__ Wt,
    const float* __restrict__ cvec, float* __restrict__ out)
{
    __shared__ unsigned short sAm[32 * ASTRIDE];
    __shared__ unsigned short sB[256 * ASTRIDE];
    __shared__ float sBias[256];

    const int t = threadIdx.x, w = t >> 6, lane = t & 63;
    const int m_lo = lane & 15, quad = lane >> 4;
    const int row0 = blockIdx.x * 32;
    sBias[t] = cvec[t];

    f32x4_t acc[2][4];
#pragma unroll
    for (int a = 0; a < 2; ++a)
#pragma unroll
        for (int b = 0; b < 4; ++b)
#pragma unroll
            for (int e = 0; e < 4; ++e) acc[a][b][e] = 0.f;

    for (int ks = 0; ks < 16; ++ks) {
        const int k0 = ks * 32;
        __syncthreads();
        if (t < 128) {  // A tile 32x32
            bf16x8_t v = *(const bf16x8_t*)(A + (size_t)(row0 + (t >> 2)) * 512 + k0 + (t & 3) * 8);
            unsigned short* d = &sAm[(t >> 2) * ASTRIDE + (t & 3) * 8];
            *(bf16x4_t*)d       = __builtin_shufflevector(v, v, 0, 1, 2, 3);
            *(bf16x4_t*)(d + 4) = __builtin_shufflevector(v, v, 4, 5, 6, 7);
        }
        {               // B tile 256x32, thread t stages n-row t
            const unsigned short* src = Wt + (size_t)t * 512 + k0;
            unsigned short* d = &sB[t * ASTRIDE];
#pragma unroll
            for (int j = 0; j < 4; ++j) {
                bf16x8_t v = *(const bf16x8_t*)(src + j * 8);
                *(bf16x4_t*)(d + j * 8)     = __builtin_shufflevector(v, v, 0, 1, 2, 3);
                *(bf16x4_t*)(d + j * 8 + 4) = __builtin_shufflevector(v, v, 4, 5, 6, 7);
            }
        }
        __syncthreads();
        bf16x8_t a0, a1;
        {
            const unsigned short* p = &sAm[m_lo * ASTRIDE + quad * 8];
            bf16x4_t lo = *(const bf16x4_t*)p, hi = *(const bf16x4_t*)(p + 4);
            a0 = __builtin_shufflevector(lo, hi, 0, 1, 2, 3, 4, 5, 6, 7);
            p += 16 * ASTRIDE;
            lo = *(const bf16x4_t*)p; hi = *(const bf16x4_t*)(p + 4);
            a1 = __builtin_shufflevector(lo, hi, 0, 1, 2, 3, 4, 5, 6, 7);
        }
#pragma unroll
        for (int nt = 0; nt < 4; ++nt) {
            const unsigned short* p = &sB[(w * 64 + nt * 16 + m_lo) * ASTRIDE + quad * 8];
            bf16x4_t lo = *(const bf16x4_t*)p, hi = *(const bf16x4_t*)(p + 4);
            bf16x8_t b = __builtin_shufflevector(lo, hi, 0, 1, 2, 3, 4, 5, 6, 7);
            acc[0][nt] = MFMA16(a0, b, acc[0][nt]);
            acc[1][nt] = MFMA16(a1, b, acc[1][nt]);
        }
    }

#pragma unroll
    for (int mt = 0; mt < 2; ++mt)
#pragma unroll
        for (int nt = 0; nt < 4; ++nt) {
            const int col = w * 64 + nt * 16 + m_lo;
#pragma unroll
            for (int r = 0; r < 4; ++r) {
                const int row = row0 + mt * 16 + quad * 4 + r;
                out[(size_t)row * 256 + col] = tanhf(acc[mt][nt][r] + sBias[col]);
            }
        }
}

// ---------------------------------------------------------------------------
extern "C" void kernel_launch(void* const* d_in, const int* in_sizes, int n_in,
                              void* d_out, int out_size, void* d_ws, size_t ws_size,
                              hipStream_t stream) {
    const float* features = (const float*)d_in[0];
    const float* key      = (const float*)d_in[1];
    const float* adj      = (const float*)d_in[2];
    const float* W_d  = (const float*)d_in[3];
    const float* b_d  = (const float*)d_in[4];
    const float* W_o  = (const float*)d_in[5];
    const float* b_o  = (const float*)d_in[6];
    const float* W_a  = (const float*)d_in[7];
    const float* b_a  = (const float*)d_in[8];
    const float* W_ao = (const float*)d_in[9];
    const float* b_ao = (const float*)d_in[10];

    float* out1 = (float*)d_out;
    float* out2 = out1 + (size_t)8192 * 256;

    char* ws = (char*)d_ws;
    unsigned short* XcatN = (unsigned short*)(ws);                 // [8192][512] bf16, 8 MB
    unsigned short* Kcat  = (unsigned short*)(ws +  8388608);      // [8192][512] bf16, 8 MB
    unsigned short* Xt    = (unsigned short*)(ws + 16777216);      // [512][8192] bf16, 8 MB
    unsigned short* Upart = (unsigned short*)(ws + 25165824);      // [4][8192][512] bf16, 32 MB
    float*          sSp   = (float*)         (ws + 58720256);      // [4][8192] f32
    unsigned short* W1t   = (unsigned short*)(ws + 58851328);      // [256][512] bf16
    unsigned short* W2t   = (unsigned short*)(ws + 59113472);      // [256][512] bf16
    float*          c1    = (float*)         (ws + 59375616);      // [256]
    float*          c2    = (float*)         (ws + 59376640);      // [256]

    dim3 blk(256);
    transpose_f32_bf16<<<dim3(256, 8), blk, 0, stream>>>(features, Xt, 8192, 256);
    transpose_f32_bf16<<<dim3(256, 8), blk, 0, stream>>>(key, Xt + (size_t)256 * 8192, 8192, 256);
    pack_half<<<4096, blk, 0, stream>>>(features, (unsigned*)XcatN);
    pack_half<<<4096, blk, 0, stream>>>(key, (unsigned*)Kcat);
    compose1<<<512, blk, 0, stream>>>(W_d, W_o, W1t);
    compose2<<<512, blk, 0, stream>>>(W_a, W_ao, W2t);
    biasC<<<1, blk, 0, stream>>>(b_d, b_o, b_a, b_ao, W_o, W_ao, c1, c2);

    exp_gemm<<<256, dim3(1024), 0, stream>>>(adj, Xt, Upart, sSp);
    finalize_agg<<<8192, blk, 0, stream>>>((const unsigned*)Upart, sSp,
                                           (unsigned*)XcatN, (unsigned*)Kcat);

    gemm_out<<<256, blk, 0, stream>>>(XcatN, W1t, c1, out1);
    gemm_out<<<256, blk, 0, stream>>>(Kcat,  W2t, c2, out2);
}